// Round 4
// baseline (4157.699 us; speedup 1.0000x reference)
//
#include <hip/hip_runtime.h>

#define SEQ 512
#define BATCH 64
#define NN 1024
#define SS 64

// barrier that does NOT drain vmcnt: each wave settles its own LDS/SMEM ops,
// then s_barrier. Outstanding global loads/stores stay in flight across it.
#define RAW_BARRIER() asm volatile("s_waitcnt lgkmcnt(0)\n\ts_barrier" ::: "memory")

// ---- transpose W1,W2 (1024x1024 f32) into workspace: Wt[i*N+j] = W[j*N+i] ----
__global__ void transpose2(const float* __restrict__ A, const float* __restrict__ Bm,
                           float* __restrict__ At, float* __restrict__ Bt) {
    __shared__ float tile[32][33];
    const float* in = blockIdx.z ? Bm : A;
    float* out      = blockIdx.z ? Bt : At;
    int bx = blockIdx.x * 32, by = blockIdx.y * 32;
    int tx = threadIdx.x, ty = threadIdx.y;   // block 32x8
#pragma unroll
    for (int r = 0; r < 32; r += 8)
        tile[ty + r][tx] = in[(by + ty + r) * NN + (bx + tx)];
    __syncthreads();
#pragma unroll
    for (int r = 0; r < 32; r += 8)
        out[(bx + ty + r) * NN + (by + tx)] = tile[tx][ty + r];
}

// 16-lane inclusive prefix scan via DPP row_shr (pure VALU, no LDS).
__device__ __forceinline__ int dpp_scan16(int x) {
    x += __builtin_amdgcn_update_dpp(0, x, 0x111, 0xF, 0xF, false); // row_shr:1
    x += __builtin_amdgcn_update_dpp(0, x, 0x112, 0xF, 0xF, false); // row_shr:2
    x += __builtin_amdgcn_update_dpp(0, x, 0x114, 0xF, 0xF, false); // row_shr:4
    x += __builtin_amdgcn_update_dpp(0, x, 0x118, 0xF, 0xF, false); // row_shr:8
    return x;
}

// ---- main LIF kernel: 1 block per batch element, thread n = neuron n ----
__global__ __launch_bounds__(1024) void lif_kernel(
    const float* __restrict__ W1T, const float* __restrict__ W2T,
    const float* __restrict__ decay1, const float* __restrict__ decay2,
    const float* __restrict__ th1, const float* __restrict__ th2,
    const float* __restrict__ init1, const float* __restrict__ init2,
    const int* __restrict__ inp_ids, const int* __restrict__ inp_num,
    float* __restrict__ out)
{
    const int b = blockIdx.x;
    const int n = threadIdx.x;
    const int lane = n & 63;
    const int wid  = n >> 6;

    __shared__ int slotsA[NN];                 // only used on (rare) layer-1 spike steps
    __shared__ int wtA[16];                    // packed: cnt | cnt2<<16
    __shared__ int wtB[16];

    float v1 = init1[b * NN + n];
    float v2 = init2[b * NN + n];
    const float d1 = decay1[n], d2 = decay2[n];
    const float t1 = th1[n],    t2 = th2[n];
    const float t1b = __fmul_rn(0.9f, t1);
    const float t2b = __fmul_rn(0.9f, t2);
    const float omd1 = __fadd_rn(1.0f, -d1);
    const float omd2 = __fadd_rn(1.0f, -d2);

    // output layout (floats): ids1 | ids2 | cnt1 | cnt2 | st1 | st2
    float* out_ids1 = out;
    float* out_ids2 = out + (size_t)SEQ * BATCH * SS;
    float* out_cnt1 = out + (size_t)2 * SEQ * BATCH * SS;
    float* out_cnt2 = out_cnt1 + (size_t)SEQ * BATCH * 2;
    float* out_st1  = out_cnt2 + (size_t)SEQ * BATCH * 2;
    float* out_st2  = out_st1  + (size_t)SEQ * BATCH * NN;

    const unsigned long long lmask_lt = (1ull << lane) - 1ull;

    // identity-init slotsA: stale remainder reads in the rare gather stay in [0,1023]
    slotsA[n] = n;

    // ---- prologue: scalar ids/num for step 0, issue num-limited gather(0) ----
    float a[64];
    int num = inp_num[b];
    {
        const int* idsg = inp_ids + (size_t)b * SS;    // block-uniform -> s_load path
        const int nch = (num + 15) >> 4;
#pragma unroll
        for (int c = 0; c < 4; ++c)
            if (c < nch) {                              // block-uniform branch
#pragma unroll
                for (int j = 0; j < 16; ++j)
                    a[c * 16 + j] = W1T[((size_t)idsg[c * 16 + j] << 10) + n];
            }
    }

    for (int t = 0; t < SEQ; ++t) {
        // ---- layer 1: accumulate I1 from in-flight a[] (issued last iteration) ----
        float I1;
        {
            const int nfull = num >> 4;
            const int rem   = num & 15;
            float s0 = 0.0f, s1 = 0.0f, s2 = 0.0f, s3 = 0.0f;
#pragma unroll
            for (int c = 0; c < 4; ++c)
                if (c < nfull) {                        // full chunks: no masking
#pragma unroll
                    for (int j = 0; j < 16; j += 4) {
                        s0 = __fadd_rn(s0, a[c * 16 + j + 0]);
                        s1 = __fadd_rn(s1, a[c * 16 + j + 1]);
                        s2 = __fadd_rn(s2, a[c * 16 + j + 2]);
                        s3 = __fadd_rn(s3, a[c * 16 + j + 3]);
                    }
                }
            if (rem) {
                const int base = nfull << 4;
#pragma unroll
                for (int j = 0; j < 16; j += 4) {
                    s0 = __fadd_rn(s0, (j + 0 < rem) ? a[base + j + 0] : 0.0f);
                    s1 = __fadd_rn(s1, (j + 1 < rem) ? a[base + j + 1] : 0.0f);
                    s2 = __fadd_rn(s2, (j + 2 < rem) ? a[base + j + 2] : 0.0f);
                    s3 = __fadd_rn(s3, (j + 3 < rem) ? a[base + j + 3] : 0.0f);
                }
            }
            I1 = __fadd_rn(__fadd_rn(s0, s1), __fadd_rn(s2, s3));
        }

        v1 = __fadd_rn(__fmul_rn(d1, v1), __fmul_rn(omd1, I1));
        const bool spk1  = v1 > t1;
        const bool near1 = v1 > t1b;

        const unsigned long long bal1 = __ballot(spk1);
        const unsigned long long bal2 = __ballot(near1);
        if (lane == 0)
            wtA[wid] = (int)__popcll(bal1) | ((int)__popcll(bal2) << 16);

        RAW_BARRIER();                                              // B1 (no vmcnt drain)

        // packed cross-wave scan: 1 ds_read + DPP (VALU) + readlane (scalar)
        int xA = dpp_scan16(wtA[lane & 15]);
        const int totPackA  = __builtin_amdgcn_readlane(xA, 15);
        const int offPackA  = wid ? __builtin_amdgcn_readlane(xA, wid - 1) : 0;
        const int totalA  = totPackA & 0xFFFF;
        const int total2A = totPackA >> 16;
        const int waveoff = offPackA & 0xFFFF;

        const int spk_lt1 = waveoff + (int)__popcll(bal1 & lmask_lt);
        const int slot1 = spk1 ? spk_lt1 : (totalA + n - spk_lt1);
        if (spk1) v1 = 0.0f;

        // scalar prefetch of next step's ids/num (issued AFTER B1 so B1's lgkm
        // drain never waits on a cold HBM s_load; consumed below, pre-B3)
        const int tn = (t + 1 < SEQ) ? t + 1 : 0;   // wrapped: last-iter loads harmless
        const int num_next = inp_num[tn * BATCH + b];
        const int* idsg_next = inp_ids + ((size_t)tn * BATCH + b) * SS;

        // ---- layer 2: I2 = sum over spiking j (ascending) of W2T[j][n] ----
        // totalA is block-uniform -> conditional barrier is legal; skipped when no spikes
        float I2 = 0.0f;
        if (totalA > 0) {
            if (spk1) slotsA[spk_lt1] = n;     // only spiking slots needed
            RAW_BARRIER();                                          // B2 (rare)
            const int kfull = totalA >> 4;
            const int krem  = totalA & 15;
            int kbase = 0;
            for (int r = 0; r < kfull; ++r, kbase += 16) {
                float aa[16];
#pragma unroll
                for (int j = 0; j < 16; ++j)
                    aa[j] = W2T[(slotsA[kbase + j] << 10) + n];
#pragma unroll
                for (int j = 0; j < 16; ++j)
                    I2 = __fadd_rn(I2, aa[j]);
            }
            if (krem) {
                float aa[16];
#pragma unroll
                for (int j = 0; j < 16; ++j)   // stale entries are valid ids (identity init)
                    aa[j] = W2T[(slotsA[kbase + j] << 10) + n];
#pragma unroll
                for (int j = 0; j < 16; ++j)
                    if (j < krem) I2 = __fadd_rn(I2, aa[j]);
            }
        }

        v2 = __fadd_rn(__fmul_rn(d2, v2), __fmul_rn(omd2, I2));
        const bool spk2  = v2 > t2;
        const bool near2 = v2 > t2b;

        const unsigned long long bal3 = __ballot(spk2);
        const unsigned long long bal4 = __ballot(near2);
        if (lane == 0)
            wtB[wid] = (int)__popcll(bal3) | ((int)__popcll(bal4) << 16);

        // ---- issue gather(t+1) NOW: num-limited, older than this step's stores,
        // latency covered by B3 + scan2 + stores + loop-back ----
        {
            const int nch = (num_next + 15) >> 4;
#pragma unroll
            for (int c = 0; c < 4; ++c)
                if (c < nch) {
#pragma unroll
                    for (int j = 0; j < 16; ++j)
                        a[c * 16 + j] = W1T[((size_t)idsg_next[c * 16 + j] << 10) + n];
                }
        }

        RAW_BARRIER();                                              // B3 (no vmcnt drain)

        int xB = dpp_scan16(wtB[lane & 15]);
        const int totPackB  = __builtin_amdgcn_readlane(xB, 15);
        const int offPackB  = wid ? __builtin_amdgcn_readlane(xB, wid - 1) : 0;
        const int totalB   = totPackB & 0xFFFF;
        const int total2B  = totPackB >> 16;
        const int waveoffB = offPackB & 0xFFFF;

        const int spk_lt2 = waveoffB + (int)__popcll(bal3 & lmask_lt);
        const int slot2 = spk2 ? spk_lt2 : (totalB + n - spk_lt2);
        if (spk2) v2 = 0.0f;

        // ---- all stores for step t (younger than gather(t+1) loads) ----
        const size_t row = (size_t)t * BATCH + b;
        if (slot1 < SS)
            __builtin_nontemporal_store((float)n, &out_ids1[row * SS + slot1]);
        if (slot2 < SS)
            __builtin_nontemporal_store((float)n, &out_ids2[row * SS + slot2]);
        if (n == 0) {
            __builtin_nontemporal_store((float)totalA,  &out_cnt1[row * 2 + 0]);
            __builtin_nontemporal_store((float)total2A, &out_cnt1[row * 2 + 1]);
            __builtin_nontemporal_store((float)totalB,  &out_cnt2[row * 2 + 0]);
            __builtin_nontemporal_store((float)total2B, &out_cnt2[row * 2 + 1]);
        }
        __builtin_nontemporal_store(v1, &out_st1[row * NN + n]);
        __builtin_nontemporal_store(v2, &out_st2[row * NN + n]);

        num = num_next;
    }
}

extern "C" void kernel_launch(void* const* d_in, const int* in_sizes, int n_in,
                              void* d_out, int out_size, void* d_ws, size_t ws_size,
                              hipStream_t stream) {
    const float* W1     = (const float*)d_in[0];
    const float* W2     = (const float*)d_in[1];
    const float* decay1 = (const float*)d_in[2];
    const float* decay2 = (const float*)d_in[3];
    const float* th1    = (const float*)d_in[4];
    const float* th2    = (const float*)d_in[5];
    const float* init1  = (const float*)d_in[6];
    const float* init2  = (const float*)d_in[7];
    const int* inp_ids  = (const int*)d_in[8];
    const int* inp_num  = (const int*)d_in[9];
    float* out = (float*)d_out;

    float* W1T = (float*)d_ws;
    float* W2T = W1T + (size_t)NN * NN;

    dim3 tb(32, 8, 1), tg(NN / 32, NN / 32, 2);
    transpose2<<<tg, tb, 0, stream>>>(W1, W2, W1T, W2T);
    lif_kernel<<<BATCH, NN, 0, stream>>>(W1T, W2T, decay1, decay2, th1, th2,
                                         init1, init2, inp_ids, inp_num, out);
}

// Round 5
// 1607.682 us; speedup vs baseline: 2.5861x; 2.5861x over previous
//
#include <hip/hip_runtime.h>

#define SEQ 512
#define BATCH 64
#define NN 1024
#define SS 64

// barrier that does NOT drain vmcnt: each wave settles its own LDS/SMEM ops,
// then s_barrier. Outstanding global loads/stores stay in flight across it.
#define RAW_BARRIER() asm volatile("s_waitcnt lgkmcnt(0)\n\ts_barrier" ::: "memory")

// ---- transpose W1,W2 (1024x1024 f32) into workspace: Wt[i*N+j] = W[j*N+i] ----
__global__ void transpose2(const float* __restrict__ A, const float* __restrict__ Bm,
                           float* __restrict__ At, float* __restrict__ Bt) {
    __shared__ float tile[32][33];
    const float* in = blockIdx.z ? Bm : A;
    float* out      = blockIdx.z ? Bt : At;
    int bx = blockIdx.x * 32, by = blockIdx.y * 32;
    int tx = threadIdx.x, ty = threadIdx.y;   // block 32x8
#pragma unroll
    for (int r = 0; r < 32; r += 8)
        tile[ty + r][tx] = in[(by + ty + r) * NN + (bx + tx)];
    __syncthreads();
#pragma unroll
    for (int r = 0; r < 32; r += 8)
        out[(bx + ty + r) * NN + (by + tx)] = tile[tx][ty + r];
}

// 16-lane inclusive prefix scan via DPP row_shr (pure VALU, no LDS).
__device__ __forceinline__ int dpp_scan16(int x) {
    x += __builtin_amdgcn_update_dpp(0, x, 0x111, 0xF, 0xF, false); // row_shr:1
    x += __builtin_amdgcn_update_dpp(0, x, 0x112, 0xF, 0xF, false); // row_shr:2
    x += __builtin_amdgcn_update_dpp(0, x, 0x114, 0xF, 0xF, false); // row_shr:4
    x += __builtin_amdgcn_update_dpp(0, x, 0x118, 0xF, 0xF, false); // row_shr:8
    return x;
}

// ---- main LIF kernel: 1 block per batch element, thread n = neuron n ----
// __launch_bounds__(1024, 4): 16 waves/block = 4 waves/EU -> VGPR cap 128.
// (Round 4 lesson: without the 2nd arg the compiler capped at 64 and spilled
// the prefetch array to scratch -> 5 GB of HBM scratch traffic.)
__global__ __launch_bounds__(1024, 4) void lif_kernel(
    const float* __restrict__ W1T, const float* __restrict__ W2T,
    const float* __restrict__ decay1, const float* __restrict__ decay2,
    const float* __restrict__ th1, const float* __restrict__ th2,
    const float* __restrict__ init1, const float* __restrict__ init2,
    const int* __restrict__ inp_ids, const int* __restrict__ inp_num,
    float* __restrict__ out)
{
    const int b = blockIdx.x;
    const int n = threadIdx.x;
    const int lane = n & 63;
    const int wid  = n >> 6;

    __shared__ int slotsA[NN];       // only used on (rare) layer-1 spike steps
    __shared__ int wt[2][2][16];     // [step parity][layer][wave], packed cnt|cnt2<<16

    float v1 = init1[b * NN + n];
    float v2 = init2[b * NN + n];
    const float d1 = decay1[n], d2 = decay2[n];
    const float t1 = th1[n],    t2 = th2[n];
    const float t1b = __fmul_rn(0.9f, t1);
    const float t2b = __fmul_rn(0.9f, t2);
    const float omd1 = __fadd_rn(1.0f, -d1);
    const float omd2 = __fadd_rn(1.0f, -d2);

    // output layout (floats): ids1 | ids2 | cnt1 | cnt2 | st1 | st2
    float* out_ids1 = out;
    float* out_ids2 = out + (size_t)SEQ * BATCH * SS;
    float* out_cnt1 = out + (size_t)2 * SEQ * BATCH * SS;
    float* out_cnt2 = out_cnt1 + (size_t)SEQ * BATCH * 2;
    float* out_st1  = out_cnt2 + (size_t)SEQ * BATCH * 2;
    float* out_st2  = out_st1  + (size_t)SEQ * BATCH * NN;

    const unsigned long long lmask_lt = (1ull << lane) - 1ull;

    // identity-init slotsA: stale remainder reads in the rare gather stay in [0,1023]
    slotsA[n] = n;

    // ---- prologue: prefetch gather(0), first up-to-48 rows (16-chunk granular) ----
    float a_pre[48];
    int num = inp_num[b];
    const int* idsg = inp_ids + (size_t)b * SS;   // block-uniform -> s_load path
    {
        const int pc  = (num + 15) >> 4;
        const int pch = pc > 3 ? 3 : pc;
#pragma unroll
        for (int c = 0; c < 3; ++c)
            if (c < pch) {                         // block-uniform branch
#pragma unroll
                for (int j = 0; j < 16; ++j)
                    a_pre[c * 16 + j] = W1T[((size_t)idsg[c * 16 + j] << 10) + n];
            }
    }

    for (int t = 0; t < SEQ; ++t) {
        const int p  = t & 1;
        const int tn = (t + 1 < SEQ) ? t + 1 : 0;  // wrapped: last-iter prefetch harmless
        const int num_next  = inp_num[tn * BATCH + b];
        const int* idsn = inp_ids + ((size_t)tn * BATCH + b) * SS;

        // ---- remainder rows 48..num-1 for THIS step (issued before accumulate) ----
        float a_rem[16];
        const int rem3 = num - 48;                 // <= 16
        if (rem3 > 0) {
#pragma unroll
            for (int j = 0; j < 16; ++j)           // ids[] always has 64 valid entries
                a_rem[j] = W1T[((size_t)idsg[48 + j] << 10) + n];
        }

        // ---- layer 1 accumulate: a_pre chunks (in flight since last step) + a_rem ----
        float I1;
        {
            float s0 = 0.0f, s1 = 0.0f, s2 = 0.0f, s3 = 0.0f;
#pragma unroll
            for (int c = 0; c < 3; ++c) {
                const int lim = num - (c << 4);
                if (lim >= 16) {
#pragma unroll
                    for (int j = 0; j < 16; j += 4) {
                        s0 = __fadd_rn(s0, a_pre[c * 16 + j + 0]);
                        s1 = __fadd_rn(s1, a_pre[c * 16 + j + 1]);
                        s2 = __fadd_rn(s2, a_pre[c * 16 + j + 2]);
                        s3 = __fadd_rn(s3, a_pre[c * 16 + j + 3]);
                    }
                } else if (lim > 0) {
#pragma unroll
                    for (int j = 0; j < 16; j += 4) {
                        s0 = __fadd_rn(s0, (j + 0 < lim) ? a_pre[c * 16 + j + 0] : 0.0f);
                        s1 = __fadd_rn(s1, (j + 1 < lim) ? a_pre[c * 16 + j + 1] : 0.0f);
                        s2 = __fadd_rn(s2, (j + 2 < lim) ? a_pre[c * 16 + j + 2] : 0.0f);
                        s3 = __fadd_rn(s3, (j + 3 < lim) ? a_pre[c * 16 + j + 3] : 0.0f);
                    }
                }
            }
            if (rem3 > 0) {
#pragma unroll
                for (int j = 0; j < 16; j += 4) {
                    s0 = __fadd_rn(s0, (j + 0 < rem3) ? a_rem[j + 0] : 0.0f);
                    s1 = __fadd_rn(s1, (j + 1 < rem3) ? a_rem[j + 1] : 0.0f);
                    s2 = __fadd_rn(s2, (j + 2 < rem3) ? a_rem[j + 2] : 0.0f);
                    s3 = __fadd_rn(s3, (j + 3 < rem3) ? a_rem[j + 3] : 0.0f);
                }
            }
            I1 = __fadd_rn(__fadd_rn(s0, s1), __fadd_rn(s2, s3));
        }

        v1 = __fadd_rn(__fmul_rn(d1, v1), __fmul_rn(omd1, I1));
        const bool spk1  = v1 > t1;
        const bool near1 = v1 > t1b;
        const unsigned long long bal1 = __ballot(spk1);
        const unsigned long long bal2 = __ballot(near1);
        if (lane == 0)
            wt[p][0][wid] = (int)__popcll(bal1) | ((int)__popcll(bal2) << 16);

        // ---- speculative layer 2 (I2 = 0, the overwhelmingly common case) ----
        // exact when totalA==0: v2' = d2*v2 + omd2*0 == d2*v2
        const float v2s = __fmul_rn(d2, v2);
        {
            const bool spk2s  = v2s > t2;
            const bool near2s = v2s > t2b;
            const unsigned long long b3 = __ballot(spk2s);
            const unsigned long long b4 = __ballot(near2s);
            if (lane == 0)
                wt[p][1][wid] = (int)__popcll(b3) | ((int)__popcll(b4) << 16);
        }

        // ---- prefetch gather(t+1): issued PRE-barrier so latency is covered by
        // barrier + scans + stores + loop-back. num-limited (16-chunk granular). ----
        {
            const int pc  = (num_next + 15) >> 4;
            const int pch = pc > 3 ? 3 : pc;
#pragma unroll
            for (int c = 0; c < 3; ++c)
                if (c < pch) {
#pragma unroll
                    for (int j = 0; j < 16; ++j)
                        a_pre[c * 16 + j] = W1T[((size_t)idsn[c * 16 + j] << 10) + n];
                }
        }

        RAW_BARRIER();                              // single barrier (common case)

        // ---- scan layer 1 ----
        int xA = dpp_scan16(wt[p][0][lane & 15]);
        const int totPackA = __builtin_amdgcn_readlane(xA, 15);
        const int offPackA = wid ? __builtin_amdgcn_readlane(xA, wid - 1) : 0;
        const int totalA  = totPackA & 0xFFFF;
        const int total2A = totPackA >> 16;
        const int waveoff = offPackA & 0xFFFF;
        const int spk_lt1 = waveoff + (int)__popcll(bal1 & lmask_lt);
        const int slot1   = spk1 ? spk_lt1 : (totalA + n - spk_lt1);
        if (spk1) v1 = 0.0f;

        // ---- layer 2 resolve: accept speculation, or rare corrective path ----
        bool spk2;
        if (totalA > 0) {
            if (spk1) slotsA[spk_lt1] = n;          // only spiking slots needed
            RAW_BARRIER();                          // rare
            float I2 = 0.0f;
            const int kfull = totalA >> 4;
            const int krem  = totalA & 15;
            int kbase = 0;
            for (int r = 0; r < kfull; ++r, kbase += 16) {
                float aa[16];
#pragma unroll
                for (int j = 0; j < 16; ++j)
                    aa[j] = W2T[(slotsA[kbase + j] << 10) + n];
#pragma unroll
                for (int j = 0; j < 16; ++j)
                    I2 = __fadd_rn(I2, aa[j]);
            }
            if (krem) {
                float aa[16];
#pragma unroll
                for (int j = 0; j < 16; ++j)        // stale entries valid (identity init)
                    aa[j] = W2T[(slotsA[kbase + j] << 10) + n];
#pragma unroll
                for (int j = 0; j < 16; ++j)
                    if (j < krem) I2 = __fadd_rn(I2, aa[j]);
            }
            const float v2r = __fadd_rn(__fmul_rn(d2, v2), __fmul_rn(omd2, I2));
            spk2 = v2r > t2;
            const bool near2r = v2r > t2b;
            const unsigned long long b3 = __ballot(spk2);
            const unsigned long long b4 = __ballot(near2r);
            if (lane == 0)
                wt[p][1][wid] = (int)__popcll(b3) | ((int)__popcll(b4) << 16);
            RAW_BARRIER();                          // rare
            v2 = v2r;
        } else {
            v2 = v2s;
            spk2 = v2 > t2;
        }

        // ---- scan layer 2 (common code; wt[p][1] is spec or corrected) ----
        int xB = dpp_scan16(wt[p][1][lane & 15]);
        const int totPackB = __builtin_amdgcn_readlane(xB, 15);
        const int offPackB = wid ? __builtin_amdgcn_readlane(xB, wid - 1) : 0;
        const int totalB   = totPackB & 0xFFFF;
        const int total2B  = totPackB >> 16;
        const int waveoffB = offPackB & 0xFFFF;
        const unsigned long long bal3 = __ballot(spk2);
        const int spk_lt2 = waveoffB + (int)__popcll(bal3 & lmask_lt);
        const int slot2   = spk2 ? spk_lt2 : (totalB + n - spk_lt2);
        if (spk2) v2 = 0.0f;

        // ---- stores for step t (NT, fire-and-forget; never drained at barriers) ----
        const size_t row = (size_t)t * BATCH + b;
        if (slot1 < SS)
            __builtin_nontemporal_store((float)n, &out_ids1[row * SS + slot1]);
        if (slot2 < SS)
            __builtin_nontemporal_store((float)n, &out_ids2[row * SS + slot2]);
        if (n == 0) {
            __builtin_nontemporal_store((float)totalA,  &out_cnt1[row * 2 + 0]);
            __builtin_nontemporal_store((float)total2A, &out_cnt1[row * 2 + 1]);
            __builtin_nontemporal_store((float)totalB,  &out_cnt2[row * 2 + 0]);
            __builtin_nontemporal_store((float)total2B, &out_cnt2[row * 2 + 1]);
        }
        __builtin_nontemporal_store(v1, &out_st1[row * NN + n]);
        __builtin_nontemporal_store(v2, &out_st2[row * NN + n]);

        num  = num_next;
        idsg = idsn;
    }
}

extern "C" void kernel_launch(void* const* d_in, const int* in_sizes, int n_in,
                              void* d_out, int out_size, void* d_ws, size_t ws_size,
                              hipStream_t stream) {
    const float* W1     = (const float*)d_in[0];
    const float* W2     = (const float*)d_in[1];
    const float* decay1 = (const float*)d_in[2];
    const float* decay2 = (const float*)d_in[3];
    const float* th1    = (const float*)d_in[4];
    const float* th2    = (const float*)d_in[5];
    const float* init1  = (const float*)d_in[6];
    const float* init2  = (const float*)d_in[7];
    const int* inp_ids  = (const int*)d_in[8];
    const int* inp_num  = (const int*)d_in[9];
    float* out = (float*)d_out;

    float* W1T = (float*)d_ws;
    float* W2T = W1T + (size_t)NN * NN;

    dim3 tb(32, 8, 1), tg(NN / 32, NN / 32, 2);
    transpose2<<<tg, tb, 0, stream>>>(W1, W2, W1T, W2T);
    lif_kernel<<<BATCH, NN, 0, stream>>>(W1T, W2T, decay1, decay2, th1, th2,
                                         init1, init2, inp_ids, inp_num, out);
}